// Round 8
// baseline (877.752 us; speedup 1.0000x reference)
//
#include <hip/hip_runtime.h>
#include <hip/hip_bf16.h>

// OldODEFunc: B=8192, S=268, H=1024, R=8, A=256, E=4, Z=8, P=4.
// R15: direct-B-to-registers. Base = R13 (best, 560.3 µs). Mains were
// LDS-throughput-bound: 128KB LDS R+W per block per K-tile (A read 4x by
// column-waves, B 2x by row-waves) -> ~20µs/GEMM floor at 85B/cy. B now
// loads global->reg per wave (weights L2-resident; 64B-segment pattern),
// removing B's LDS writes+reads: 128->80 KB/tile. Same operands, same MFMA
// order -> bit-identical. B-regs double-buffered via NAMED arrays bbA/bbB
// in an unroll-by-2 loop (no runtime reg indexing); counted vmcnt(6)
// (2 A-stage g2l16 + 4 B-reg loads per iter). LDS 32KB/block.
// R14's add_delta fusion + conv merge reverted (regressed, rule #19).

typedef unsigned short u16;
typedef __bf16 bf16x8 __attribute__((ext_vector_type(8)));
typedef float f32x4 __attribute__((ext_vector_type(4)));

__device__ __forceinline__ u16 f2b(float f) {
  union { float f; unsigned u; } v; v.f = f;
  unsigned r = v.u + 0x7FFFu + ((v.u >> 16) & 1u);   // RNE
  return (u16)(r >> 16);
}
__device__ __forceinline__ float b2f(u16 s) {
  union { unsigned u; float f; } v; v.u = ((unsigned)s) << 16;
  return v.f;
}

// async global->LDS, 16B per lane; lds dest = wave-uniform base + lane*16
__device__ __forceinline__ void g2l16(const u16* g, u16* l) {
  __builtin_amdgcn_global_load_lds(
      (__attribute__((address_space(1))) void*)g,
      (__attribute__((address_space(3))) void*)l, 16, 0, 0);
}

// ---------------- main GEMM ----------------
// C(128M x 128N) = A(128 x KK, row-major, LDA) @ W(N x KK)^T.
// Dynamic LDS: 2 bufs x 128*64 bf16 (A only) = 32 KB -> 2 blocks/CU (grid-capped).
// 8 waves (512 thr): wave grid 2x4, wave-tile 64x32, acc[4][2]. 16 waves/CU.
// A: g2l16-staged, chunk-swizzled (logical c at phys c ^ (row&7)).
// B: DIRECT global->reg, natural k-offset (A's phys^sw == s*4+quad == B's chunk).
// Prefetch depth 1, counted vmcnt(6); unroll-by-2 with named bbA/bbB.
// MODE 0: relu->bf16  1: tanh->bf16  2: tanh(+resid in-place)->bf16
// MODE 3: f32 out, cols<nreal
template<int MODE, int KK, int LDA>
__global__ __launch_bounds__(512, 4)
void pgemm(const u16* __restrict__ A, const u16* __restrict__ W,
           const float* __restrict__ bias, const u16* __restrict__ resid,
           void* __restrict__ outp, int nreal, int ldo)
{
  extern __shared__ __align__(16) u16 sm[];
  constexpr int BUFSZ = 128 * 64;     // u16 per A buffer (16 KB)

  const int tid  = threadIdx.x;
  const int wave = tid >> 6;
  const int lane = tid & 63;
  const int m0 = blockIdx.x << 7;   // grid.x = m -> XCD = m%8 (A-affinity)
  const int n0 = blockIdx.y << 7;
  const int wr = wave >> 2, wc = wave & 3;       // 2x4 waves, 64x32 each
  const int lrow = lane & 15, quad = lane >> 4;
  const int sw = lrow & 7;

  // A staging: each g2l16 covers 8 rows x 64 elems (64 lanes x 8 elems).
  const int srow  = lane >> 3;                        // 0..7 row in group
  const int sperm = ((lane & 7) ^ (srow & 7)) << 3;   // swizzled elem offset

  const u16* Ag = A + (size_t)(m0 + wave * 16 + srow) * LDA + sperm;
  // direct-B: lane (lrow,quad) reads row n0+wc*32+j*16+lrow, k = ko+s*32+quad*8
  const u16* Bg = W + (size_t)(n0 + wc * 32 + lrow) * KK + quad * 8;

  f32x4 acc[4][2];
#pragma unroll
  for (int i = 0; i < 4; i++)
#pragma unroll
    for (int j = 0; j < 2; j++) { f32x4 z = {0.f,0.f,0.f,0.f}; acc[i][j] = z; }

  // stage A K-tile p into LDS buffer buf (2 g2l16 per wave)
  auto stageA = [&](int p, int buf) {
    const int ko = p << 6;
    u16* aD = sm + buf * BUFSZ;
    g2l16(Ag + ko,                   aD + (wave * 16 + 0) * 64);
    g2l16(Ag + (size_t)8 * LDA + ko, aD + (wave * 16 + 8) * 64);
  };
  // load B K-tile p into named regs (4 x 16B global loads per wave)
  auto loadB = [&](int p, bf16x8 (&bb)[2][2]) {
    const int ko = p << 6;
#pragma unroll
    for (int j = 0; j < 2; j++)
#pragma unroll
      for (int s = 0; s < 2; s++)
        bb[j][s] = *(const bf16x8*)(Bg + (size_t)j * 16 * KK + ko + s * 32);
  };
  auto compute = [&](const u16* aS, const bf16x8 (&bb)[2][2]) {
#pragma unroll
    for (int s = 0; s < 2; s++) {
      const int phys = (s * 4 + quad) ^ sw;
      bf16x8 af[4];
#pragma unroll
      for (int i = 0; i < 4; i++)
        af[i] = *(const bf16x8*)&aS[(wr * 64 + i * 16 + lrow) * 64 + phys * 8];
      __builtin_amdgcn_s_setprio(1);
#pragma unroll
      for (int i = 0; i < 4; i++)
#pragma unroll
        for (int j = 0; j < 2; j++)
          acc[i][j] = __builtin_amdgcn_mfma_f32_16x16x32_bf16(af[i], bb[j][s], acc[i][j], 0, 0, 0);
      __builtin_amdgcn_s_setprio(0);
    }
  };

  constexpr int P = KK / 64;   // 6 or 16 — always even
  bf16x8 bbA[2][2], bbB[2][2];

  stageA(0, 0); loadB(0, bbA);   // 6 loads outstanding

  for (int p = 0; p < P; p += 2) {
    // ---- even tile p: compute slot0/bbA, prefetch p+1 -> slot1/bbB ----
    if (p + 1 < P) {
      stageA(p + 1, 1); loadB(p + 1, bbB);
      asm volatile("s_waitcnt vmcnt(6)" ::: "memory");   // tile p all landed
    } else {
      asm volatile("s_waitcnt vmcnt(0)" ::: "memory");
    }
    __builtin_amdgcn_sched_barrier(0);
    __builtin_amdgcn_s_barrier();       // A(p) visible to all waves
    __builtin_amdgcn_sched_barrier(0);
    compute(sm, bbA);
    __builtin_amdgcn_sched_barrier(0);
    __builtin_amdgcn_s_barrier();       // readers of slot0 done
    __builtin_amdgcn_sched_barrier(0);

    // ---- odd tile p+1: compute slot1/bbB, prefetch p+2 -> slot0/bbA ----
    if (p + 2 < P) {
      stageA(p + 2, 0); loadB(p + 2, bbA);
      asm volatile("s_waitcnt vmcnt(6)" ::: "memory");   // tile p+1 landed
    } else {
      asm volatile("s_waitcnt vmcnt(0)" ::: "memory");
    }
    __builtin_amdgcn_sched_barrier(0);
    __builtin_amdgcn_s_barrier();
    __builtin_amdgcn_sched_barrier(0);
    compute(sm + BUFSZ, bbB);
    __builtin_amdgcn_sched_barrier(0);
    __builtin_amdgcn_s_barrier();
    __builtin_amdgcn_sched_barrier(0);
  }

  auto th = [](float x) {
    x = fminf(fmaxf(x, -40.f), 40.f);
    float a = __builtin_amdgcn_exp2f(2.88539008177793f * x);
    return (a - 1.f) * __builtin_amdgcn_rcpf(a + 1.f);
  };

  // epilogue: C/D layout col = lane&15, row = quad*4 + reg
#pragma unroll
  for (int i = 0; i < 4; i++) {
    const int rowb = m0 + wr * 64 + i * 16 + quad * 4;
#pragma unroll
    for (int j = 0; j < 2; j++) {
      const int col = n0 + wc * 32 + j * 16 + lrow;
      const float bi = (col < nreal) ? bias[col] : 0.f;
#pragma unroll
      for (int r = 0; r < 4; r++) {
        const int row = rowb + r;
        float v = acc[i][j][r] + bi;
        if (MODE == 0) {
          v = v > 0.f ? v : 0.f;
          ((u16*)outp)[(size_t)row * ldo + col] = f2b(v);
        } else if (MODE == 1) {
          ((u16*)outp)[(size_t)row * ldo + col] = f2b(th(v));
        } else if (MODE == 2) {
          v += b2f(resid[(size_t)row * ldo + col]);
          ((u16*)outp)[(size_t)row * ldo + col] = f2b(th(v));
        } else if (MODE == 3) {
          if (col < nreal) ((float*)outp)[(size_t)row * ldo + col] = v;
        }
      }
    }
  }
}

// ---------------- small GEMM for ta path ----------------
// 64M x 128N tile, BK=64, LDS-staged, xor swizzle, plain bf16 out.
__global__ __launch_bounds__(256, 4)
void gemm_bt(const u16* __restrict__ A, const u16* __restrict__ B,
             const float* __restrict__ bias, u16* __restrict__ outp,
             int K, int lda, int ldo)
{
  __shared__ __align__(16) u16 As[64 * 64];
  __shared__ __align__(16) u16 Bs[128 * 64];
  const int tid  = threadIdx.x;
  const int wave = tid >> 6;
  const int lane = tid & 63;
  const int m0 = blockIdx.y << 6;
  const int n0 = blockIdx.x << 7;
  const int wr = wave >> 1, wc = wave & 1;
  const int lrow = lane & 15, quad = lane >> 4;
  const int srow  = lane >> 3;
  const int sperm = ((lane & 7) ^ (srow & 7)) << 3;

  const u16* Ag0 = A + (size_t)(m0 + wave * 16 +  0 + srow) * lda + sperm;
  const u16* Ag1 = A + (size_t)(m0 + wave * 16 +  8 + srow) * lda + sperm;
  const u16* Bg0 = B + (size_t)(n0 + wave * 32 +  0 + srow) * K + sperm;
  const u16* Bg1 = B + (size_t)(n0 + wave * 32 +  8 + srow) * K + sperm;
  const u16* Bg2 = B + (size_t)(n0 + wave * 32 + 16 + srow) * K + sperm;
  const u16* Bg3 = B + (size_t)(n0 + wave * 32 + 24 + srow) * K + sperm;
  u16* Al0 = &As[(wave * 16 +  0) * 64];
  u16* Al1 = &As[(wave * 16 +  8) * 64];
  u16* Bl0 = &Bs[(wave * 32 +  0) * 64];
  u16* Bl1 = &Bs[(wave * 32 +  8) * 64];
  u16* Bl2 = &Bs[(wave * 32 + 16) * 64];
  u16* Bl3 = &Bs[(wave * 32 + 24) * 64];

  f32x4 acc[2][4];
#pragma unroll
  for (int i = 0; i < 2; i++)
#pragma unroll
    for (int j = 0; j < 4; j++) { f32x4 z = {0.f,0.f,0.f,0.f}; acc[i][j] = z; }

  const int swz = lrow & 7;

  for (int k0 = 0; k0 < K; k0 += 64) {
    if (k0) __syncthreads();
    g2l16(Ag0 + k0, Al0);
    g2l16(Ag1 + k0, Al1);
    g2l16(Bg0 + k0, Bl0);
    g2l16(Bg1 + k0, Bl1);
    g2l16(Bg2 + k0, Bl2);
    g2l16(Bg3 + k0, Bl3);
    __syncthreads();
#pragma unroll
    for (int s = 0; s < 2; s++) {
      const int c = (s * 4 + quad) ^ swz;
      bf16x8 af[2], bfr[4];
#pragma unroll
      for (int i = 0; i < 2; i++)
        af[i] = *(const bf16x8*)&As[(wr * 32 + i * 16 + lrow) * 64 + c * 8];
#pragma unroll
      for (int j = 0; j < 4; j++)
        bfr[j] = *(const bf16x8*)&Bs[(wc * 64 + j * 16 + lrow) * 64 + c * 8];
#pragma unroll
      for (int i = 0; i < 2; i++)
#pragma unroll
        for (int j = 0; j < 4; j++)
          acc[i][j] = __builtin_amdgcn_mfma_f32_16x16x32_bf16(af[i], bfr[j], acc[i][j], 0, 0, 0);
    }
  }

#pragma unroll
  for (int i = 0; i < 2; i++) {
    const int rowb = m0 + wr * 32 + i * 16 + quad * 4;
#pragma unroll
    for (int j = 0; j < 4; j++) {
      const int col = n0 + wc * 64 + j * 16 + lrow;
      const float bi = bias[col];
#pragma unroll
      for (int r = 0; r < 4; r++)
        outp[(size_t)(rowb + r) * ldo + col] = f2b(acc[i][j][r] + bi);
    }
  }
}

// ---------------- prep ----------------
__global__ void conv_bulk(const float* __restrict__ w1, const float* __restrict__ w2,
                          u16* __restrict__ o1, u16* __restrict__ o2)
{
  const int n4 = (8 * 1024 * 1024) / 4;
  int i = blockIdx.x * 256 + threadIdx.x;
  const float* src; u16* dst;
  if (i < n4) { src = w1; dst = o1; }
  else        { i -= n4; if (i >= n4) return; src = w2; dst = o2; }
  float4 v = ((const float4*)src)[i];
  unsigned p0 = (unsigned)f2b(v.x) | ((unsigned)f2b(v.y) << 16);
  unsigned p1 = (unsigned)f2b(v.z) | ((unsigned)f2b(v.w) << 16);
  uint2 pk; pk.x = p0; pk.y = p1;
  ((uint2*)dst)[i] = pk;
}

// W0 pad(1024x384), Wf pad(384x1024), taA(256x256), taB(256x256), x_bf(8192x384)
__global__ void conv_misc(const float* __restrict__ W0, const float* __restrict__ Wf,
                          const float* __restrict__ ta_in_w, const float* __restrict__ ta_out_w,
                          const float* __restrict__ state, const float* __restrict__ t,
                          u16* __restrict__ w0_bf, u16* __restrict__ wf_bf,
                          u16* __restrict__ taA, u16* __restrict__ taB,
                          u16* __restrict__ x_bf)
{
  int i = blockIdx.x * 256 + threadIdx.x;
  const int nW0 = 1024 * 384;
  const int nWf = 384 * 1024;
  const int nTa = 256 * 256;
  const int nX  = 8192 * 384;
  if (i < nW0) {
    int o = i / 384, k = i - o * 384;
    w0_bf[i] = (k < 270) ? f2b(W0[o * 270 + k]) : (u16)0;
    return;
  }
  i -= nW0;
  if (i < nWf) {
    int n = i >> 10;
    wf_bf[i] = (n < 268) ? f2b(Wf[i]) : (u16)0;
    return;
  }
  i -= nWf;
  if (i < nTa) { taA[i] = f2b(ta_in_w[512 * 256 + i]); return; }
  i -= nTa;
  if (i < nTa) { taB[i] = f2b(ta_out_w[i]); return; }
  i -= nTa;
  if (i < nX) {
    int r = i / 384, c = i - r * 384;
    u16 v;
    if (c < 268) v = f2b(state[r * 268 + c]);
    else if (c == 268) { float ang = t[0] * 0.2617993877991494f; v = f2b(sinf(ang)); }
    else if (c == 269) { float ang = t[0] * 0.2617993877991494f; v = f2b(cosf(ang)); }
    else v = 0;
    x_bf[i] = v;
  }
}

// out += 0.1*delta
__global__ void add_delta(float* __restrict__ out, const u16* __restrict__ eh,
                          const float* __restrict__ state,
                          const float* __restrict__ lp_in_w, const float* __restrict__ lp_in_b,
                          const float* __restrict__ lp_out_w, const float* __restrict__ lp_out_b,
                          const float* __restrict__ loc_proj_w, const float* __restrict__ loc_proj_b,
                          const float* __restrict__ loc_back_w, const float* __restrict__ loc_back_b)
{
  const int idx = blockIdx.x * 256 + threadIdx.x;
  if (idx >= 8192 * 268) return;
  const int row = idx / 268;
  const int col = idx - row * 268;
  if (col < 256) {
    out[idx] += 0.1f * (b2f(eh[row * 256 + col]) - state[idx]);
  } else if (col < 264) {
    const float* srow = state + row * 268 + 256;
    float locp[4], vv[4], dd[4];
#pragma unroll
    for (int e = 0; e < 4; e++) {
      float s = loc_proj_b[e];
#pragma unroll
      for (int z = 0; z < 8; z++) s += loc_proj_w[e * 8 + z] * srow[z];
      locp[e] = s;
    }
#pragma unroll
    for (int e = 0; e < 4; e++) {
      float s = lp_in_b[8 + e];
#pragma unroll
      for (int j = 0; j < 4; j++) s += lp_in_w[(8 + e) * 4 + j] * locp[j];
      vv[e] = s;
    }
#pragma unroll
    for (int e = 0; e < 4; e++) {
      float s = lp_out_b[e];
#pragma unroll
      for (int j = 0; j < 4; j++) s += lp_out_w[e * 4 + j] * vv[j];
      dd[e] = s - locp[e];
    }
    const int z = col - 256;
    float s = loc_back_b[z];
#pragma unroll
    for (int e = 0; e < 4; e++) s += loc_back_w[z * 4 + e] * dd[e];
    out[idx] += 0.1f * s;
  }
}

extern "C" void kernel_launch(void* const* d_in, const int* in_sizes, int n_in,
                              void* d_out, int out_size, void* d_ws, size_t ws_size,
                              hipStream_t stream)
{
  const float* t          = (const float*)d_in[0];
  const float* state      = (const float*)d_in[1];
  const float* W0         = (const float*)d_in[2];
  const float* b0         = (const float*)d_in[3];
  const float* rW1        = (const float*)d_in[4];
  const float* rb1        = (const float*)d_in[5];
  const float* rW2        = (const float*)d_in[6];
  const float* rb2        = (const float*)d_in[7];
  const float* Wf         = (const float*)d_in[8];
  const float* bfv        = (const float*)d_in[9];
  const float* lp_in_w    = (const float*)d_in[10];
  const float* lp_in_b    = (const float*)d_in[11];
  const float* lp_out_w   = (const float*)d_in[12];
  const float* lp_out_b   = (const float*)d_in[13];
  const float* ta_in_w    = (const float*)d_in[14];
  const float* ta_in_b    = (const float*)d_in[15];
  const float* ta_out_w   = (const float*)d_in[16];
  const float* ta_out_b   = (const float*)d_in[17];
  const float* loc_proj_w = (const float*)d_in[18];
  const float* loc_proj_b = (const float*)d_in[19];
  const float* loc_back_w = (const float*)d_in[20];
  const float* loc_back_b = (const float*)d_in[21];
  float* out = (float*)d_out;

  char* ws = (char*)d_ws;
  auto alloc = [&](size_t bytes) { char* p = ws; ws += (bytes + 255) & ~(size_t)255; return p; };
  u16* rw1_bf = (u16*)alloc((size_t)8 * 1024 * 1024 * 2);
  u16* rw2_bf = (u16*)alloc((size_t)8 * 1024 * 1024 * 2);
  u16* w0_bf  = (u16*)alloc((size_t)1024 * 384 * 2);
  u16* wf_bf  = (u16*)alloc((size_t)384 * 1024 * 2);
  u16* taA_bf = (u16*)alloc((size_t)256 * 256 * 2);
  u16* taB_bf = (u16*)alloc((size_t)256 * 256 * 2);
  u16* x_bf   = (u16*)alloc((size_t)8192 * 384 * 2);
  u16* h_bf   = (u16*)alloc((size_t)8192 * 1024 * 2);
  u16* tmp_bf = (u16*)alloc((size_t)8192 * 1024 * 2);
  u16* v2_bf  = (u16*)alloc((size_t)8192 * 256 * 2);
  u16* eh_bf  = (u16*)alloc((size_t)8192 * 256 * 2);

  const int lds = 2 * 128 * 64 * 2;   // 32768 B (2 A-only bufs x 16 KB)
  hipFuncSetAttribute(reinterpret_cast<const void*>(pgemm<0, 384, 384>),
                      hipFuncAttributeMaxDynamicSharedMemorySize, lds);
  hipFuncSetAttribute(reinterpret_cast<const void*>(pgemm<1, 1024, 1024>),
                      hipFuncAttributeMaxDynamicSharedMemorySize, lds);
  hipFuncSetAttribute(reinterpret_cast<const void*>(pgemm<2, 1024, 1024>),
                      hipFuncAttributeMaxDynamicSharedMemorySize, lds);
  hipFuncSetAttribute(reinterpret_cast<const void*>(pgemm<3, 1024, 1024>),
                      hipFuncAttributeMaxDynamicSharedMemorySize, lds);

  conv_bulk<<<16384, 256, 0, stream>>>(rW1, rW2, rw1_bf, rw2_bf);
  conv_misc<<<15872, 256, 0, stream>>>(W0, Wf, ta_in_w, ta_out_w, state, t,
                                       w0_bf, wf_bf, taA_bf, taB_bf, x_bf);

  // h = relu(x @ W0^T + b0)   K padded 270->384
  pgemm<0, 384, 384><<<dim3(64, 8), 512, lds, stream>>>(x_bf, w0_bf, b0, nullptr, h_bf, 1024, 1024);

  // 8 residual blocks
  for (int r = 0; r < 8; r++) {
    pgemm<1, 1024, 1024><<<dim3(64, 8), 512, lds, stream>>>(
        h_bf, rw1_bf + ((size_t)r << 20), rb1 + (r << 10), nullptr, tmp_bf, 1024, 1024);
    pgemm<2, 1024, 1024><<<dim3(64, 8), 512, lds, stream>>>(
        tmp_bf, rw2_bf + ((size_t)r << 20), rb2 + (r << 10), h_bf, h_bf, 1024, 1024);
  }

  // ta path: v2 = x[:, :256] @ taA^T + b ; eh = v2 @ taB^T + b
  gemm_bt<<<dim3(2, 128), 256, 0, stream>>>(x_bf, taA_bf, ta_in_b + 512, v2_bf, 256, 384, 256);
  gemm_bt<<<dim3(2, 128), 256, 0, stream>>>(v2_bf, taB_bf, ta_out_b, eh_bf, 256, 256, 256);

  // core = h @ Wf^T + bf -> f32 out (N padded 268->384)
  pgemm<3, 1024, 1024><<<dim3(64, 3), 512, lds, stream>>>(h_bf, wf_bf, bfv, nullptr, out, 268, 268);

  // out += 0.1*delta
  add_delta<<<8576, 256, 0, stream>>>(out, eh_bf, state,
                                      lp_in_w, lp_in_b, lp_out_w, lp_out_b,
                                      loc_proj_w, loc_proj_b, loc_back_w, loc_back_b);
}

// Round 9
// 566.913 us; speedup vs baseline: 1.5483x; 1.5483x over previous
//
#include <hip/hip_runtime.h>
#include <hip/hip_bf16.h>

// OldODEFunc: B=8192, S=268, H=1024, R=8, A=256, E=4, Z=8, P=4.
// R16: revert to R13 (verified best, 560.3 µs) + fuse the ta path.
// R14 (add_delta fusion, -22µs) and R15 (direct-B regs, -317µs: B-fragment
// global loads are 16x64B scattered segments -> 16x L2 transactions) both
// reverted. pgemm/conv/add_delta are byte-identical to R13.
// New: ta_fused replaces 2x gemm_bt — per block (64 rows) compute
// v2 = x[:, :256]@taA^T + b in LDS (padded [64][264] row-major, 2-way-free),
// then eh = v2@taB^T + b. Same k0/s MFMA chain + same bf16 quantization of
// v2 -> bit-identical; saves a launch + v2's 8MB round-trip + a drain.

typedef unsigned short u16;
typedef __bf16 bf16x8 __attribute__((ext_vector_type(8)));
typedef float f32x4 __attribute__((ext_vector_type(4)));

__device__ __forceinline__ u16 f2b(float f) {
  union { float f; unsigned u; } v; v.f = f;
  unsigned r = v.u + 0x7FFFu + ((v.u >> 16) & 1u);   // RNE
  return (u16)(r >> 16);
}
__device__ __forceinline__ float b2f(u16 s) {
  union { unsigned u; float f; } v; v.u = ((unsigned)s) << 16;
  return v.f;
}

// async global->LDS, 16B per lane; lds dest = wave-uniform base + lane*16
__device__ __forceinline__ void g2l16(const u16* g, u16* l) {
  __builtin_amdgcn_global_load_lds(
      (__attribute__((address_space(1))) void*)g,
      (__attribute__((address_space(3))) void*)l, 16, 0, 0);
}

// ---------------- main GEMM (R13, byte-identical) ----------------
// C(128M x 128N) = A(128 x KK, row-major, LDA) @ W(N x KK)^T.
// Dynamic LDS: 2 bufs x (128+128)*64 bf16 = 64 KB -> 2 blocks/CU.
// 8 waves (512 thr): wave grid 2x4, wave-tile 64x32, acc[4][2].
// 16 waves/CU = 4 waves/SIMD for latency hiding.
// Counted-vmcnt prefetch depth 1: stage p+1 during compute p, vmcnt(4).
// MODE 0: relu->bf16  1: tanh->bf16  2: tanh(+resid in-place)->bf16
// MODE 3: f32 out, cols<nreal
template<int MODE, int KK, int LDA>
__global__ __launch_bounds__(512, 4)
void pgemm(const u16* __restrict__ A, const u16* __restrict__ W,
           const float* __restrict__ bias, const u16* __restrict__ resid,
           void* __restrict__ outp, int nreal, int ldo)
{
  extern __shared__ __align__(16) u16 sm[];
  constexpr int BUFSZ = (128 + 128) * 64;     // u16 per buffer (32 KB)

  const int tid  = threadIdx.x;
  const int wave = tid >> 6;
  const int lane = tid & 63;
  const int m0 = blockIdx.x << 7;   // grid.x = m -> XCD = m%8 (A-affinity)
  const int n0 = blockIdx.y << 7;
  const int wr = wave >> 2, wc = wave & 3;       // 2x4 waves, 64x32 each
  const int lrow = lane & 15, quad = lane >> 4;
  const int sw = lrow & 7;

  // staging: each g2l16 covers 8 rows x 64 elems (64 lanes x 8 elems).
  // Per wave: 2 A-groups + 2 B-groups (rows wave*16 + {0,8}) = 4 loads/tile.
  const int srow  = lane >> 3;                        // 0..7 row in group
  const int sperm = ((lane & 7) ^ (srow & 7)) << 3;   // swizzled elem offset

  const u16* Ag = A + (size_t)(m0 + wave * 16 + srow) * LDA + sperm;
  const u16* Bg = W + (size_t)(n0 + wave * 16 + srow) * KK + sperm;

  f32x4 acc[4][2];
#pragma unroll
  for (int i = 0; i < 4; i++)
#pragma unroll
    for (int j = 0; j < 2; j++) { f32x4 z = {0.f,0.f,0.f,0.f}; acc[i][j] = z; }

  // stage K-tile p into buffer buf (4 loads per wave: 2 A + 2 B groups)
  auto stage = [&](int p, int buf) {
    const int ko = p << 6;
    u16* aD = sm + buf * BUFSZ;
    u16* bD = aD + 128 * 64;
    g2l16(Ag + ko,                        aD + (wave * 16 + 0) * 64);
    g2l16(Ag + (size_t)8 * LDA + ko,      aD + (wave * 16 + 8) * 64);
    g2l16(Bg + ko,                        bD + (wave * 16 + 0) * 64);
    g2l16(Bg + (size_t)8 * KK + ko,       bD + (wave * 16 + 8) * 64);
  };

  constexpr int P = KK / 64;

  stage(0, 0);   // prologue: tile 0 in flight (4 loads outstanding)

  for (int p = 0; p < P; ++p) {
    // issue tile p+1 into the other buffer BEFORE computing tile p.
    // WAR safe: buffer (p+1)&1 was last read in iter p-1; those ds_reads
    // completed (lgkm consumed by MFMAs) before the end-of-iter-(p-1)
    // barrier, which precedes this point.
    if (p + 1 < P) {
      stage(p + 1, (p + 1) & 1);
      // wait tile p's 4 oldest loads; tile p+1's 4 stay in flight (T4)
      asm volatile("s_waitcnt vmcnt(4)" ::: "memory");
    } else {
      asm volatile("s_waitcnt vmcnt(0)" ::: "memory");
    }
    __builtin_amdgcn_sched_barrier(0);
    __builtin_amdgcn_s_barrier();       // all waves: tile p visible
    __builtin_amdgcn_sched_barrier(0);

    const u16* aS = sm + (p & 1) * BUFSZ;
    const u16* bS = aS + 128 * 64;
#pragma unroll
    for (int s = 0; s < 2; s++) {
      const int phys = (s * 4 + quad) ^ sw;
      bf16x8 af[4], bfr[2];
#pragma unroll
      for (int i = 0; i < 4; i++)
        af[i] = *(const bf16x8*)&aS[(wr * 64 + i * 16 + lrow) * 64 + phys * 8];
#pragma unroll
      for (int j = 0; j < 2; j++)
        bfr[j] = *(const bf16x8*)&bS[(wc * 32 + j * 16 + lrow) * 64 + phys * 8];
      __builtin_amdgcn_s_setprio(1);
#pragma unroll
      for (int i = 0; i < 4; i++)
#pragma unroll
        for (int j = 0; j < 2; j++)
          acc[i][j] = __builtin_amdgcn_mfma_f32_16x16x32_bf16(af[i], bfr[j], acc[i][j], 0, 0, 0);
      __builtin_amdgcn_s_setprio(0);
    }
    __builtin_amdgcn_sched_barrier(0);
    __builtin_amdgcn_s_barrier();       // readers of buf p done -> next stage may overwrite
    __builtin_amdgcn_sched_barrier(0);
  }

  auto th = [](float x) {
    x = fminf(fmaxf(x, -40.f), 40.f);
    float a = __builtin_amdgcn_exp2f(2.88539008177793f * x);
    return (a - 1.f) * __builtin_amdgcn_rcpf(a + 1.f);
  };

  // epilogue: C/D layout col = lane&15, row = quad*4 + reg
#pragma unroll
  for (int i = 0; i < 4; i++) {
    const int rowb = m0 + wr * 64 + i * 16 + quad * 4;
#pragma unroll
    for (int j = 0; j < 2; j++) {
      const int col = n0 + wc * 32 + j * 16 + lrow;
      const float bi = (col < nreal) ? bias[col] : 0.f;
#pragma unroll
      for (int r = 0; r < 4; r++) {
        const int row = rowb + r;
        float v = acc[i][j][r] + bi;
        if (MODE == 0) {
          v = v > 0.f ? v : 0.f;
          ((u16*)outp)[(size_t)row * ldo + col] = f2b(v);
        } else if (MODE == 1) {
          ((u16*)outp)[(size_t)row * ldo + col] = f2b(th(v));
        } else if (MODE == 2) {
          v += b2f(resid[(size_t)row * ldo + col]);
          ((u16*)outp)[(size_t)row * ldo + col] = f2b(th(v));
        } else if (MODE == 3) {
          if (col < nreal) ((float*)outp)[(size_t)row * ldo + col] = v;
        }
      }
    }
  }
}

// ---------------- fused ta path ----------------
// Per block: 64 rows. Phase 1: v2[64][256] = x[:, :256] @ taA^T + b1 -> LDS
// (bf16, padded row-major [64][264]). Phase 2: eh = v2 @ taB^T + b2 -> global.
// 4 waves, wave-tile 64M x 64N (wave w owns cols w*64..+63), acc[4][4].
// Same (k0, s) MFMA chain + same bf16 quantization as the two gemm_bt
// dispatches it replaces -> bit-identical eh.
__global__ __launch_bounds__(256, 2)
void ta_fused(const u16* __restrict__ x, const u16* __restrict__ taA,
              const u16* __restrict__ taB,
              const float* __restrict__ b1, const float* __restrict__ b2,
              u16* __restrict__ eh)
{
  extern __shared__ __align__(16) u16 smf[];
  u16* As1 = smf;                 // [64*64]   x tile (swizzled chunks)
  u16* Bs  = smf + 64 * 64;       // [256*64]  taA / taB tile (swizzled)
  u16* v2L = Bs + 256 * 64;       // [64*264]  padded row-major v2 bf16

  const int tid  = threadIdx.x;
  const int wave = tid >> 6;
  const int lane = tid & 63;
  const int m0 = blockIdx.x << 6;
  const int lrow = lane & 15, quad = lane >> 4;
  const int sw = lrow & 7;
  const int srow  = lane >> 3;
  const int sperm = ((lane & 7) ^ (srow & 7)) << 3;

  const u16* Ag0 = x + (size_t)(m0 + wave * 16 + 0 + srow) * 384 + sperm;
  const u16* Ag1 = x + (size_t)(m0 + wave * 16 + 8 + srow) * 384 + sperm;

  f32x4 acc[4][4];
#pragma unroll
  for (int i = 0; i < 4; i++)
#pragma unroll
    for (int j = 0; j < 4; j++) { f32x4 z = {0.f,0.f,0.f,0.f}; acc[i][j] = z; }

  // ---- phase 1: v2 = x[:, :256] @ taA^T ----
  for (int k0 = 0; k0 < 256; k0 += 64) {
    if (k0) __syncthreads();
    g2l16(Ag0 + k0, &As1[(wave * 16 + 0) * 64]);
    g2l16(Ag1 + k0, &As1[(wave * 16 + 8) * 64]);
#pragma unroll
    for (int g = 0; g < 8; g++)
      g2l16(taA + (size_t)(wave * 64 + g * 8 + srow) * 256 + sperm + k0,
            &Bs[(wave * 64 + g * 8) * 64]);
    __syncthreads();
#pragma unroll
    for (int s = 0; s < 2; s++) {
      const int c = (s * 4 + quad) ^ sw;
      bf16x8 af[4], bfr[4];
#pragma unroll
      for (int i = 0; i < 4; i++)
        af[i] = *(const bf16x8*)&As1[(i * 16 + lrow) * 64 + c * 8];
#pragma unroll
      for (int j = 0; j < 4; j++)
        bfr[j] = *(const bf16x8*)&Bs[(wave * 64 + j * 16 + lrow) * 64 + c * 8];
#pragma unroll
      for (int i = 0; i < 4; i++)
#pragma unroll
        for (int j = 0; j < 4; j++)
          acc[i][j] = __builtin_amdgcn_mfma_f32_16x16x32_bf16(af[i], bfr[j], acc[i][j], 0, 0, 0);
    }
  }
  __syncthreads();   // all Bs/As1 reads done

  // v2 -> LDS (same f2b quantization point as the original v2_bf store)
#pragma unroll
  for (int i = 0; i < 4; i++)
#pragma unroll
    for (int j = 0; j < 4; j++) {
      const int col = wave * 64 + j * 16 + lrow;
      const float bi = b1[col];
#pragma unroll
      for (int r = 0; r < 4; r++) {
        const int row = i * 16 + quad * 4 + r;
        v2L[row * 264 + col] = f2b(acc[i][j][r] + bi);
      }
    }
#pragma unroll
  for (int i = 0; i < 4; i++)
#pragma unroll
    for (int j = 0; j < 4; j++) { f32x4 z = {0.f,0.f,0.f,0.f}; acc[i][j] = z; }
  __syncthreads();   // v2L visible

  // ---- phase 2: eh = v2 @ taB^T ----
  for (int k0 = 0; k0 < 256; k0 += 64) {
    if (k0) __syncthreads();
#pragma unroll
    for (int g = 0; g < 8; g++)
      g2l16(taB + (size_t)(wave * 64 + g * 8 + srow) * 256 + sperm + k0,
            &Bs[(wave * 64 + g * 8) * 64]);
    __syncthreads();
#pragma unroll
    for (int s = 0; s < 2; s++) {
      const int cl = s * 4 + quad;          // v2L is NOT chunk-swizzled
      bf16x8 af[4], bfr[4];
#pragma unroll
      for (int i = 0; i < 4; i++)
        af[i] = *(const bf16x8*)&v2L[(i * 16 + lrow) * 264 + k0 + cl * 8];
#pragma unroll
      for (int j = 0; j < 4; j++)
        bfr[j] = *(const bf16x8*)&Bs[(wave * 64 + j * 16 + lrow) * 64 + (cl ^ sw) * 8];
#pragma unroll
      for (int i = 0; i < 4; i++)
#pragma unroll
        for (int j = 0; j < 4; j++)
          acc[i][j] = __builtin_amdgcn_mfma_f32_16x16x32_bf16(af[i], bfr[j], acc[i][j], 0, 0, 0);
    }
  }

#pragma unroll
  for (int i = 0; i < 4; i++)
#pragma unroll
    for (int j = 0; j < 4; j++) {
      const int col = wave * 64 + j * 16 + lrow;
      const float bi = b2[col];
#pragma unroll
      for (int r = 0; r < 4; r++) {
        const int row = m0 + i * 16 + quad * 4 + r;
        eh[(size_t)row * 256 + col] = f2b(acc[i][j][r] + bi);
      }
    }
}

// ---------------- prep ----------------
__global__ void conv_bulk(const float* __restrict__ w1, const float* __restrict__ w2,
                          u16* __restrict__ o1, u16* __restrict__ o2)
{
  const int n4 = (8 * 1024 * 1024) / 4;
  int i = blockIdx.x * 256 + threadIdx.x;
  const float* src; u16* dst;
  if (i < n4) { src = w1; dst = o1; }
  else        { i -= n4; if (i >= n4) return; src = w2; dst = o2; }
  float4 v = ((const float4*)src)[i];
  unsigned p0 = (unsigned)f2b(v.x) | ((unsigned)f2b(v.y) << 16);
  unsigned p1 = (unsigned)f2b(v.z) | ((unsigned)f2b(v.w) << 16);
  uint2 pk; pk.x = p0; pk.y = p1;
  ((uint2*)dst)[i] = pk;
}

// W0 pad(1024x384), Wf pad(384x1024), taA(256x256), taB(256x256), x_bf(8192x384)
__global__ void conv_misc(const float* __restrict__ W0, const float* __restrict__ Wf,
                          const float* __restrict__ ta_in_w, const float* __restrict__ ta_out_w,
                          const float* __restrict__ state, const float* __restrict__ t,
                          u16* __restrict__ w0_bf, u16* __restrict__ wf_bf,
                          u16* __restrict__ taA, u16* __restrict__ taB,
                          u16* __restrict__ x_bf)
{
  int i = blockIdx.x * 256 + threadIdx.x;
  const int nW0 = 1024 * 384;
  const int nWf = 384 * 1024;
  const int nTa = 256 * 256;
  const int nX  = 8192 * 384;
  if (i < nW0) {
    int o = i / 384, k = i - o * 384;
    w0_bf[i] = (k < 270) ? f2b(W0[o * 270 + k]) : (u16)0;
    return;
  }
  i -= nW0;
  if (i < nWf) {
    int n = i >> 10;
    wf_bf[i] = (n < 268) ? f2b(Wf[i]) : (u16)0;
    return;
  }
  i -= nWf;
  if (i < nTa) { taA[i] = f2b(ta_in_w[512 * 256 + i]); return; }
  i -= nTa;
  if (i < nTa) { taB[i] = f2b(ta_out_w[i]); return; }
  i -= nTa;
  if (i < nX) {
    int r = i / 384, c = i - r * 384;
    u16 v;
    if (c < 268) v = f2b(state[r * 268 + c]);
    else if (c == 268) { float ang = t[0] * 0.2617993877991494f; v = f2b(sinf(ang)); }
    else if (c == 269) { float ang = t[0] * 0.2617993877991494f; v = f2b(cosf(ang)); }
    else v = 0;
    x_bf[i] = v;
  }
}

// out += 0.1*delta
__global__ void add_delta(float* __restrict__ out, const u16* __restrict__ eh,
                          const float* __restrict__ state,
                          const float* __restrict__ lp_in_w, const float* __restrict__ lp_in_b,
                          const float* __restrict__ lp_out_w, const float* __restrict__ lp_out_b,
                          const float* __restrict__ loc_proj_w, const float* __restrict__ loc_proj_b,
                          const float* __restrict__ loc_back_w, const float* __restrict__ loc_back_b)
{
  const int idx = blockIdx.x * 256 + threadIdx.x;
  if (idx >= 8192 * 268) return;
  const int row = idx / 268;
  const int col = idx - row * 268;
  if (col < 256) {
    out[idx] += 0.1f * (b2f(eh[row * 256 + col]) - state[idx]);
  } else if (col < 264) {
    const float* srow = state + row * 268 + 256;
    float locp[4], vv[4], dd[4];
#pragma unroll
    for (int e = 0; e < 4; e++) {
      float s = loc_proj_b[e];
#pragma unroll
      for (int z = 0; z < 8; z++) s += loc_proj_w[e * 8 + z] * srow[z];
      locp[e] = s;
    }
#pragma unroll
    for (int e = 0; e < 4; e++) {
      float s = lp_in_b[8 + e];
#pragma unroll
      for (int j = 0; j < 4; j++) s += lp_in_w[(8 + e) * 4 + j] * locp[j];
      vv[e] = s;
    }
#pragma unroll
    for (int e = 0; e < 4; e++) {
      float s = lp_out_b[e];
#pragma unroll
      for (int j = 0; j < 4; j++) s += lp_out_w[e * 4 + j] * vv[j];
      dd[e] = s - locp[e];
    }
    const int z = col - 256;
    float s = loc_back_b[z];
#pragma unroll
    for (int e = 0; e < 4; e++) s += loc_back_w[z * 4 + e] * dd[e];
    out[idx] += 0.1f * s;
  }
}

extern "C" void kernel_launch(void* const* d_in, const int* in_sizes, int n_in,
                              void* d_out, int out_size, void* d_ws, size_t ws_size,
                              hipStream_t stream)
{
  const float* t          = (const float*)d_in[0];
  const float* state      = (const float*)d_in[1];
  const float* W0         = (const float*)d_in[2];
  const float* b0         = (const float*)d_in[3];
  const float* rW1        = (const float*)d_in[4];
  const float* rb1        = (const float*)d_in[5];
  const float* rW2        = (const float*)d_in[6];
  const float* rb2        = (const float*)d_in[7];
  const float* Wf         = (const float*)d_in[8];
  const float* bfv        = (const float*)d_in[9];
  const float* lp_in_w    = (const float*)d_in[10];
  const float* lp_in_b    = (const float*)d_in[11];
  const float* lp_out_w   = (const float*)d_in[12];
  const float* lp_out_b   = (const float*)d_in[13];
  const float* ta_in_w    = (const float*)d_in[14];
  const float* ta_in_b    = (const float*)d_in[15];
  const float* ta_out_w   = (const float*)d_in[16];
  const float* ta_out_b   = (const float*)d_in[17];
  const float* loc_proj_w = (const float*)d_in[18];
  const float* loc_proj_b = (const float*)d_in[19];
  const float* loc_back_w = (const float*)d_in[20];
  const float* loc_back_b = (const float*)d_in[21];
  float* out = (float*)d_out;

  char* ws = (char*)d_ws;
  auto alloc = [&](size_t bytes) { char* p = ws; ws += (bytes + 255) & ~(size_t)255; return p; };
  u16* rw1_bf = (u16*)alloc((size_t)8 * 1024 * 1024 * 2);
  u16* rw2_bf = (u16*)alloc((size_t)8 * 1024 * 1024 * 2);
  u16* w0_bf  = (u16*)alloc((size_t)1024 * 384 * 2);
  u16* wf_bf  = (u16*)alloc((size_t)384 * 1024 * 2);
  u16* taA_bf = (u16*)alloc((size_t)256 * 256 * 2);
  u16* taB_bf = (u16*)alloc((size_t)256 * 256 * 2);
  u16* x_bf   = (u16*)alloc((size_t)8192 * 384 * 2);
  u16* h_bf   = (u16*)alloc((size_t)8192 * 1024 * 2);
  u16* tmp_bf = (u16*)alloc((size_t)8192 * 1024 * 2);
  u16* eh_bf  = (u16*)alloc((size_t)8192 * 256 * 2);

  const int lds = 2 * (128 + 128) * 64 * 2;   // 65536 B (2 bufs x 32 KB)
  hipFuncSetAttribute(reinterpret_cast<const void*>(pgemm<0, 384, 384>),
                      hipFuncAttributeMaxDynamicSharedMemorySize, lds);
  hipFuncSetAttribute(reinterpret_cast<const void*>(pgemm<1, 1024, 1024>),
                      hipFuncAttributeMaxDynamicSharedMemorySize, lds);
  hipFuncSetAttribute(reinterpret_cast<const void*>(pgemm<2, 1024, 1024>),
                      hipFuncAttributeMaxDynamicSharedMemorySize, lds);
  hipFuncSetAttribute(reinterpret_cast<const void*>(pgemm<3, 1024, 1024>),
                      hipFuncAttributeMaxDynamicSharedMemorySize, lds);
  const int ldsT = (64 * 64 + 256 * 64 + 64 * 264) * 2;   // 74752 B
  hipFuncSetAttribute(reinterpret_cast<const void*>(ta_fused),
                      hipFuncAttributeMaxDynamicSharedMemorySize, ldsT);

  conv_bulk<<<16384, 256, 0, stream>>>(rW1, rW2, rw1_bf, rw2_bf);
  conv_misc<<<15872, 256, 0, stream>>>(W0, Wf, ta_in_w, ta_out_w, state, t,
                                       w0_bf, wf_bf, taA_bf, taB_bf, x_bf);

  // h = relu(x @ W0^T + b0)   K padded 270->384
  pgemm<0, 384, 384><<<dim3(64, 8), 512, lds, stream>>>(x_bf, w0_bf, b0, nullptr, h_bf, 1024, 1024);

  // 8 residual blocks
  for (int r = 0; r < 8; r++) {
    pgemm<1, 1024, 1024><<<dim3(64, 8), 512, lds, stream>>>(
        h_bf, rw1_bf + ((size_t)r << 20), rb1 + (r << 10), nullptr, tmp_bf, 1024, 1024);
    pgemm<2, 1024, 1024><<<dim3(64, 8), 512, lds, stream>>>(
        tmp_bf, rw2_bf + ((size_t)r << 20), rb2 + (r << 10), h_bf, h_bf, 1024, 1024);
  }

  // ta path fused: eh = (x[:, :256] @ taA^T + b1) @ taB^T + b2
  ta_fused<<<128, 256, ldsT, stream>>>(x_bf, taA_bf, taB_bf,
                                       ta_in_b + 512, ta_out_b, eh_bf);

  // core = h @ Wf^T + bf -> f32 out (N padded 268->384)
  pgemm<3, 1024, 1024><<<dim3(64, 3), 512, lds, stream>>>(h_bf, wf_bf, bfv, nullptr, out, 268, 268);

  // out += 0.1*delta
  add_delta<<<8576, 256, 0, stream>>>(out, eh_bf, state,
                                      lp_in_w, lp_in_b, lp_out_w, lp_out_b,
                                      loc_proj_w, loc_proj_b, loc_back_w, loc_back_b);
}

// Round 10
// 553.637 us; speedup vs baseline: 1.5854x; 1.0240x over previous
//
#include <hip/hip_runtime.h>
#include <hip/hip_bf16.h>

// OldODEFunc: B=8192, S=268, H=1024, R=8, A=256, E=4, Z=8, P=4.
// R17: banked wins on the frozen R13 base (best, 560.3 µs).
//  (1) K-pad for input GEMM 384->320 (real K=270): pgemm<0> P=6->5.
//  (2) add_delta fused into STANDALONE pgemm4 (Wf GEMM epilogue). R14's
//      regression is attributed to hot-template signature pollution
//      (rule #19); pgemm<1>/<2> here are byte-identical to R13.
//  (3) ta path = R13's two gemm_bt (R16's ta_fused was neutral/negative).
// All changes bit-identical by construction (exact-zero K padding; same
// f32 ops and order for the delta).

typedef unsigned short u16;
typedef __bf16 bf16x8 __attribute__((ext_vector_type(8)));
typedef float f32x4 __attribute__((ext_vector_type(4)));

__device__ __forceinline__ u16 f2b(float f) {
  union { float f; unsigned u; } v; v.f = f;
  unsigned r = v.u + 0x7FFFu + ((v.u >> 16) & 1u);   // RNE
  return (u16)(r >> 16);
}
__device__ __forceinline__ float b2f(u16 s) {
  union { unsigned u; float f; } v; v.u = ((unsigned)s) << 16;
  return v.f;
}

// async global->LDS, 16B per lane; lds dest = wave-uniform base + lane*16
__device__ __forceinline__ void g2l16(const u16* g, u16* l) {
  __builtin_amdgcn_global_load_lds(
      (__attribute__((address_space(1))) void*)g,
      (__attribute__((address_space(3))) void*)l, 16, 0, 0);
}

// ---------------- main GEMM (R13, byte-identical) ----------------
// C(128M x 128N) = A(128 x KK, row-major, LDA) @ W(N x KK)^T.
// Dynamic LDS: 2 bufs x (128+128)*64 bf16 = 64 KB -> 2 blocks/CU.
// 8 waves (512 thr): wave grid 2x4, wave-tile 64x32, acc[4][2].
// Counted-vmcnt prefetch depth 1: stage p+1 during compute p, vmcnt(4).
// MODE 0: relu->bf16  1: tanh->bf16  2: tanh(+resid in-place)->bf16
template<int MODE, int KK, int LDA>
__global__ __launch_bounds__(512, 4)
void pgemm(const u16* __restrict__ A, const u16* __restrict__ W,
           const float* __restrict__ bias, const u16* __restrict__ resid,
           void* __restrict__ outp, int nreal, int ldo)
{
  extern __shared__ __align__(16) u16 sm[];
  constexpr int BUFSZ = (128 + 128) * 64;     // u16 per buffer (32 KB)

  const int tid  = threadIdx.x;
  const int wave = tid >> 6;
  const int lane = tid & 63;
  const int m0 = blockIdx.x << 7;   // grid.x = m -> XCD = m%8 (A-affinity)
  const int n0 = blockIdx.y << 7;
  const int wr = wave >> 2, wc = wave & 3;       // 2x4 waves, 64x32 each
  const int lrow = lane & 15, quad = lane >> 4;
  const int sw = lrow & 7;

  const int srow  = lane >> 3;                        // 0..7 row in group
  const int sperm = ((lane & 7) ^ (srow & 7)) << 3;   // swizzled elem offset

  const u16* Ag = A + (size_t)(m0 + wave * 16 + srow) * LDA + sperm;
  const u16* Bg = W + (size_t)(n0 + wave * 16 + srow) * KK + sperm;

  f32x4 acc[4][2];
#pragma unroll
  for (int i = 0; i < 4; i++)
#pragma unroll
    for (int j = 0; j < 2; j++) { f32x4 z = {0.f,0.f,0.f,0.f}; acc[i][j] = z; }

  auto stage = [&](int p, int buf) {
    const int ko = p << 6;
    u16* aD = sm + buf * BUFSZ;
    u16* bD = aD + 128 * 64;
    g2l16(Ag + ko,                        aD + (wave * 16 + 0) * 64);
    g2l16(Ag + (size_t)8 * LDA + ko,      aD + (wave * 16 + 8) * 64);
    g2l16(Bg + ko,                        bD + (wave * 16 + 0) * 64);
    g2l16(Bg + (size_t)8 * KK + ko,       bD + (wave * 16 + 8) * 64);
  };

  constexpr int P = KK / 64;

  stage(0, 0);   // prologue: tile 0 in flight (4 loads outstanding)

  for (int p = 0; p < P; ++p) {
    if (p + 1 < P) {
      stage(p + 1, (p + 1) & 1);
      asm volatile("s_waitcnt vmcnt(4)" ::: "memory");
    } else {
      asm volatile("s_waitcnt vmcnt(0)" ::: "memory");
    }
    __builtin_amdgcn_sched_barrier(0);
    __builtin_amdgcn_s_barrier();       // all waves: tile p visible
    __builtin_amdgcn_sched_barrier(0);

    const u16* aS = sm + (p & 1) * BUFSZ;
    const u16* bS = aS + 128 * 64;
#pragma unroll
    for (int s = 0; s < 2; s++) {
      const int phys = (s * 4 + quad) ^ sw;
      bf16x8 af[4], bfr[2];
#pragma unroll
      for (int i = 0; i < 4; i++)
        af[i] = *(const bf16x8*)&aS[(wr * 64 + i * 16 + lrow) * 64 + phys * 8];
#pragma unroll
      for (int j = 0; j < 2; j++)
        bfr[j] = *(const bf16x8*)&bS[(wc * 32 + j * 16 + lrow) * 64 + phys * 8];
      __builtin_amdgcn_s_setprio(1);
#pragma unroll
      for (int i = 0; i < 4; i++)
#pragma unroll
        for (int j = 0; j < 2; j++)
          acc[i][j] = __builtin_amdgcn_mfma_f32_16x16x32_bf16(af[i], bfr[j], acc[i][j], 0, 0, 0);
      __builtin_amdgcn_s_setprio(0);
    }
    __builtin_amdgcn_sched_barrier(0);
    __builtin_amdgcn_s_barrier();       // readers of buf p done
    __builtin_amdgcn_sched_barrier(0);
  }

  auto th = [](float x) {
    x = fminf(fmaxf(x, -40.f), 40.f);
    float a = __builtin_amdgcn_exp2f(2.88539008177793f * x);
    return (a - 1.f) * __builtin_amdgcn_rcpf(a + 1.f);
  };

  // epilogue: C/D layout col = lane&15, row = quad*4 + reg
#pragma unroll
  for (int i = 0; i < 4; i++) {
    const int rowb = m0 + wr * 64 + i * 16 + quad * 4;
#pragma unroll
    for (int j = 0; j < 2; j++) {
      const int col = n0 + wc * 32 + j * 16 + lrow;
      const float bi = (col < nreal) ? bias[col] : 0.f;
#pragma unroll
      for (int r = 0; r < 4; r++) {
        const int row = rowb + r;
        float v = acc[i][j][r] + bi;
        if (MODE == 0) {
          v = v > 0.f ? v : 0.f;
          ((u16*)outp)[(size_t)row * ldo + col] = f2b(v);
        } else if (MODE == 1) {
          ((u16*)outp)[(size_t)row * ldo + col] = f2b(th(v));
        } else if (MODE == 2) {
          v += b2f(resid[(size_t)row * ldo + col]);
          ((u16*)outp)[(size_t)row * ldo + col] = f2b(th(v));
        }
      }
    }
  }
}

// ---------------- final GEMM + fused delta (standalone, KK=1024) -------------
// out[8192x268] = h @ Wf^T + bf + 0.1*delta. Same main-loop as pgemm; the
// epilogue applies add_delta's arithmetic (identical f32 ops/order).
__global__ __launch_bounds__(512, 4)
void pgemm4(const u16* __restrict__ A, const u16* __restrict__ W,
            const float* __restrict__ bias, const u16* __restrict__ eh,
            const float* __restrict__ state, float* __restrict__ outp,
            const float* __restrict__ lp_in_w, const float* __restrict__ lp_in_b,
            const float* __restrict__ lp_out_w, const float* __restrict__ lp_out_b,
            const float* __restrict__ loc_proj_w, const float* __restrict__ loc_proj_b,
            const float* __restrict__ loc_back_w, const float* __restrict__ loc_back_b)
{
  extern __shared__ __align__(16) u16 sm[];
  constexpr int BUFSZ = (128 + 128) * 64;
  constexpr int KK = 1024;

  const int tid  = threadIdx.x;
  const int wave = tid >> 6;
  const int lane = tid & 63;
  const int m0 = blockIdx.x << 7;
  const int n0 = blockIdx.y << 7;
  const int wr = wave >> 2, wc = wave & 3;
  const int lrow = lane & 15, quad = lane >> 4;
  const int sw = lrow & 7;
  const int srow  = lane >> 3;
  const int sperm = ((lane & 7) ^ (srow & 7)) << 3;

  const u16* Ag = A + (size_t)(m0 + wave * 16 + srow) * KK + sperm;
  const u16* Bg = W + (size_t)(n0 + wave * 16 + srow) * KK + sperm;

  f32x4 acc[4][2];
#pragma unroll
  for (int i = 0; i < 4; i++)
#pragma unroll
    for (int j = 0; j < 2; j++) { f32x4 z = {0.f,0.f,0.f,0.f}; acc[i][j] = z; }

  auto stage = [&](int p, int buf) {
    const int ko = p << 6;
    u16* aD = sm + buf * BUFSZ;
    u16* bD = aD + 128 * 64;
    g2l16(Ag + ko,                   aD + (wave * 16 + 0) * 64);
    g2l16(Ag + (size_t)8 * KK + ko,  aD + (wave * 16 + 8) * 64);
    g2l16(Bg + ko,                   bD + (wave * 16 + 0) * 64);
    g2l16(Bg + (size_t)8 * KK + ko,  bD + (wave * 16 + 8) * 64);
  };

  constexpr int P = KK / 64;
  stage(0, 0);
  for (int p = 0; p < P; ++p) {
    if (p + 1 < P) {
      stage(p + 1, (p + 1) & 1);
      asm volatile("s_waitcnt vmcnt(4)" ::: "memory");
    } else {
      asm volatile("s_waitcnt vmcnt(0)" ::: "memory");
    }
    __builtin_amdgcn_sched_barrier(0);
    __builtin_amdgcn_s_barrier();
    __builtin_amdgcn_sched_barrier(0);

    const u16* aS = sm + (p & 1) * BUFSZ;
    const u16* bS = aS + 128 * 64;
#pragma unroll
    for (int s = 0; s < 2; s++) {
      const int phys = (s * 4 + quad) ^ sw;
      bf16x8 af[4], bfr[2];
#pragma unroll
      for (int i = 0; i < 4; i++)
        af[i] = *(const bf16x8*)&aS[(wr * 64 + i * 16 + lrow) * 64 + phys * 8];
#pragma unroll
      for (int j = 0; j < 2; j++)
        bfr[j] = *(const bf16x8*)&bS[(wc * 32 + j * 16 + lrow) * 64 + phys * 8];
      __builtin_amdgcn_s_setprio(1);
#pragma unroll
      for (int i = 0; i < 4; i++)
#pragma unroll
        for (int j = 0; j < 2; j++)
          acc[i][j] = __builtin_amdgcn_mfma_f32_16x16x32_bf16(af[i], bfr[j], acc[i][j], 0, 0, 0);
      __builtin_amdgcn_s_setprio(0);
    }
    __builtin_amdgcn_sched_barrier(0);
    __builtin_amdgcn_s_barrier();
    __builtin_amdgcn_sched_barrier(0);
  }

  // epilogue: core + 0.1*delta, f32 out, cols<268
#pragma unroll
  for (int i = 0; i < 4; i++) {
    const int rowb = m0 + wr * 64 + i * 16 + quad * 4;
#pragma unroll
    for (int j = 0; j < 2; j++) {
      const int col = n0 + wc * 32 + j * 16 + lrow;
      if (col >= 268) continue;
      const float bi = bias[col];
#pragma unroll
      for (int r = 0; r < 4; r++) {
        const int row = rowb + r;
        float v = acc[i][j][r] + bi;
        float d = 0.f;
        if (col < 256) {
          d = b2f(eh[(size_t)row * 256 + col]) - state[(size_t)row * 268 + col];
        } else if (col < 264) {
          const float* srow2 = state + (size_t)row * 268 + 256;
          float locp[4], vv[4], dd[4];
#pragma unroll
          for (int e = 0; e < 4; e++) {
            float s2 = loc_proj_b[e];
#pragma unroll
            for (int z = 0; z < 8; z++) s2 += loc_proj_w[e * 8 + z] * srow2[z];
            locp[e] = s2;
          }
#pragma unroll
          for (int e = 0; e < 4; e++) {
            float s2 = lp_in_b[8 + e];
#pragma unroll
            for (int j2 = 0; j2 < 4; j2++) s2 += lp_in_w[(8 + e) * 4 + j2] * locp[j2];
            vv[e] = s2;
          }
#pragma unroll
          for (int e = 0; e < 4; e++) {
            float s2 = lp_out_b[e];
#pragma unroll
            for (int j2 = 0; j2 < 4; j2++) s2 += lp_out_w[e * 4 + j2] * vv[j2];
            dd[e] = s2 - locp[e];
          }
          const int z = col - 256;
          float s2 = loc_back_b[z];
#pragma unroll
          for (int e = 0; e < 4; e++) s2 += loc_back_w[z * 4 + e] * dd[e];
          d = s2;
        }
        outp[(size_t)row * 268 + col] = v + 0.1f * d;
      }
    }
  }
}

// ---------------- small GEMM for ta path (R13, byte-identical) --------------
__global__ __launch_bounds__(256, 4)
void gemm_bt(const u16* __restrict__ A, const u16* __restrict__ B,
             const float* __restrict__ bias, u16* __restrict__ outp,
             int K, int lda, int ldo)
{
  __shared__ __align__(16) u16 As[64 * 64];
  __shared__ __align__(16) u16 Bs[128 * 64];
  const int tid  = threadIdx.x;
  const int wave = tid >> 6;
  const int lane = tid & 63;
  const int m0 = blockIdx.y << 6;
  const int n0 = blockIdx.x << 7;
  const int wr = wave >> 1, wc = wave & 1;
  const int lrow = lane & 15, quad = lane >> 4;
  const int srow  = lane >> 3;
  const int sperm = ((lane & 7) ^ (srow & 7)) << 3;

  const u16* Ag0 = A + (size_t)(m0 + wave * 16 +  0 + srow) * lda + sperm;
  const u16* Ag1 = A + (size_t)(m0 + wave * 16 +  8 + srow) * lda + sperm;
  const u16* Bg0 = B + (size_t)(n0 + wave * 32 +  0 + srow) * K + sperm;
  const u16* Bg1 = B + (size_t)(n0 + wave * 32 +  8 + srow) * K + sperm;
  const u16* Bg2 = B + (size_t)(n0 + wave * 32 + 16 + srow) * K + sperm;
  const u16* Bg3 = B + (size_t)(n0 + wave * 32 + 24 + srow) * K + sperm;
  u16* Al0 = &As[(wave * 16 +  0) * 64];
  u16* Al1 = &As[(wave * 16 +  8) * 64];
  u16* Bl0 = &Bs[(wave * 32 +  0) * 64];
  u16* Bl1 = &Bs[(wave * 32 +  8) * 64];
  u16* Bl2 = &Bs[(wave * 32 + 16) * 64];
  u16* Bl3 = &Bs[(wave * 32 + 24) * 64];

  f32x4 acc[2][4];
#pragma unroll
  for (int i = 0; i < 2; i++)
#pragma unroll
    for (int j = 0; j < 4; j++) { f32x4 z = {0.f,0.f,0.f,0.f}; acc[i][j] = z; }

  const int swz = lrow & 7;

  for (int k0 = 0; k0 < K; k0 += 64) {
    if (k0) __syncthreads();
    g2l16(Ag0 + k0, Al0);
    g2l16(Ag1 + k0, Al1);
    g2l16(Bg0 + k0, Bl0);
    g2l16(Bg1 + k0, Bl1);
    g2l16(Bg2 + k0, Bl2);
    g2l16(Bg3 + k0, Bl3);
    __syncthreads();
#pragma unroll
    for (int s = 0; s < 2; s++) {
      const int c = (s * 4 + quad) ^ swz;
      bf16x8 af[2], bfr[4];
#pragma unroll
      for (int i = 0; i < 2; i++)
        af[i] = *(const bf16x8*)&As[(wr * 32 + i * 16 + lrow) * 64 + c * 8];
#pragma unroll
      for (int j = 0; j < 4; j++)
        bfr[j] = *(const bf16x8*)&Bs[(wc * 64 + j * 16 + lrow) * 64 + c * 8];
#pragma unroll
      for (int i = 0; i < 2; i++)
#pragma unroll
        for (int j = 0; j < 4; j++)
          acc[i][j] = __builtin_amdgcn_mfma_f32_16x16x32_bf16(af[i], bfr[j], acc[i][j], 0, 0, 0);
    }
  }

#pragma unroll
  for (int i = 0; i < 2; i++) {
    const int rowb = m0 + wr * 32 + i * 16 + quad * 4;
#pragma unroll
    for (int j = 0; j < 4; j++) {
      const int col = n0 + wc * 64 + j * 16 + lrow;
      const float bi = bias[col];
#pragma unroll
      for (int r = 0; r < 4; r++)
        outp[(size_t)(rowb + r) * ldo + col] = f2b(acc[i][j][r] + bi);
    }
  }
}

// ---------------- prep ----------------
__global__ void conv_bulk(const float* __restrict__ w1, const float* __restrict__ w2,
                          u16* __restrict__ o1, u16* __restrict__ o2)
{
  const int n4 = (8 * 1024 * 1024) / 4;
  int i = blockIdx.x * 256 + threadIdx.x;
  const float* src; u16* dst;
  if (i < n4) { src = w1; dst = o1; }
  else        { i -= n4; if (i >= n4) return; src = w2; dst = o2; }
  float4 v = ((const float4*)src)[i];
  unsigned p0 = (unsigned)f2b(v.x) | ((unsigned)f2b(v.y) << 16);
  unsigned p1 = (unsigned)f2b(v.z) | ((unsigned)f2b(v.w) << 16);
  uint2 pk; pk.x = p0; pk.y = p1;
  ((uint2*)dst)[i] = pk;
}

// W0 pad(1024x320), Wf pad(384x1024), taA(256x256), taB(256x256), x_bf(8192x320)
__global__ void conv_misc(const float* __restrict__ W0, const float* __restrict__ Wf,
                          const float* __restrict__ ta_in_w, const float* __restrict__ ta_out_w,
                          const float* __restrict__ state, const float* __restrict__ t,
                          u16* __restrict__ w0_bf, u16* __restrict__ wf_bf,
                          u16* __restrict__ taA, u16* __restrict__ taB,
                          u16* __restrict__ x_bf)
{
  int i = blockIdx.x * 256 + threadIdx.x;
  const int nW0 = 1024 * 320;
  const int nWf = 384 * 1024;
  const int nTa = 256 * 256;
  const int nX  = 8192 * 320;
  if (i < nW0) {
    int o = i / 320, k = i - o * 320;
    w0_bf[i] = (k < 270) ? f2b(W0[o * 270 + k]) : (u16)0;
    return;
  }
  i -= nW0;
  if (i < nWf) {
    int n = i >> 10;
    wf_bf[i] = (n < 268) ? f2b(Wf[i]) : (u16)0;
    return;
  }
  i -= nWf;
  if (i < nTa) { taA[i] = f2b(ta_in_w[512 * 256 + i]); return; }
  i -= nTa;
  if (i < nTa) { taB[i] = f2b(ta_out_w[i]); return; }
  i -= nTa;
  if (i < nX) {
    int r = i / 320, c = i - r * 320;
    u16 v;
    if (c < 268) v = f2b(state[r * 268 + c]);
    else if (c == 268) { float ang = t[0] * 0.2617993877991494f; v = f2b(sinf(ang)); }
    else if (c == 269) { float ang = t[0] * 0.2617993877991494f; v = f2b(cosf(ang)); }
    else v = 0;
    x_bf[i] = v;
  }
}

extern "C" void kernel_launch(void* const* d_in, const int* in_sizes, int n_in,
                              void* d_out, int out_size, void* d_ws, size_t ws_size,
                              hipStream_t stream)
{
  const float* t          = (const float*)d_in[0];
  const float* state      = (const float*)d_in[1];
  const float* W0         = (const float*)d_in[2];
  const float* b0         = (const float*)d_in[3];
  const float* rW1        = (const float*)d_in[4];
  const float* rb1        = (const float*)d_in[5];
  const float* rW2        = (const float*)d_in[6];
  const float* rb2        = (const float*)d_in[7];
  const float* Wf         = (const float*)d_in[8];
  const float* bfv        = (const float*)d_in[9];
  const float* lp_in_w    = (const float*)d_in[10];
  const float* lp_in_b    = (const float*)d_in[11];
  const float* lp_out_w   = (const float*)d_in[12];
  const float* lp_out_b   = (const float*)d_in[13];
  const float* ta_in_w    = (const float*)d_in[14];
  const float* ta_in_b    = (const float*)d_in[15];
  const float* ta_out_w   = (const float*)d_in[16];
  const float* ta_out_b   = (const float*)d_in[17];
  const float* loc_proj_w = (const float*)d_in[18];
  const float* loc_proj_b = (const float*)d_in[19];
  const float* loc_back_w = (const float*)d_in[20];
  const float* loc_back_b = (const float*)d_in[21];
  float* out = (float*)d_out;

  char* ws = (char*)d_ws;
  auto alloc = [&](size_t bytes) { char* p = ws; ws += (bytes + 255) & ~(size_t)255; return p; };
  u16* rw1_bf = (u16*)alloc((size_t)8 * 1024 * 1024 * 2);
  u16* rw2_bf = (u16*)alloc((size_t)8 * 1024 * 1024 * 2);
  u16* w0_bf  = (u16*)alloc((size_t)1024 * 320 * 2);
  u16* wf_bf  = (u16*)alloc((size_t)384 * 1024 * 2);
  u16* taA_bf = (u16*)alloc((size_t)256 * 256 * 2);
  u16* taB_bf = (u16*)alloc((size_t)256 * 256 * 2);
  u16* x_bf   = (u16*)alloc((size_t)8192 * 320 * 2);
  u16* h_bf   = (u16*)alloc((size_t)8192 * 1024 * 2);
  u16* tmp_bf = (u16*)alloc((size_t)8192 * 1024 * 2);
  u16* v2_bf  = (u16*)alloc((size_t)8192 * 256 * 2);
  u16* eh_bf  = (u16*)alloc((size_t)8192 * 256 * 2);

  const int lds = 2 * (128 + 128) * 64 * 2;   // 65536 B (2 bufs x 32 KB)
  hipFuncSetAttribute(reinterpret_cast<const void*>(pgemm<0, 320, 320>),
                      hipFuncAttributeMaxDynamicSharedMemorySize, lds);
  hipFuncSetAttribute(reinterpret_cast<const void*>(pgemm<1, 1024, 1024>),
                      hipFuncAttributeMaxDynamicSharedMemorySize, lds);
  hipFuncSetAttribute(reinterpret_cast<const void*>(pgemm<2, 1024, 1024>),
                      hipFuncAttributeMaxDynamicSharedMemorySize, lds);
  hipFuncSetAttribute(reinterpret_cast<const void*>(pgemm4),
                      hipFuncAttributeMaxDynamicSharedMemorySize, lds);

  conv_bulk<<<16384, 256, 0, stream>>>(rW1, rW2, rw1_bf, rw2_bf);
  conv_misc<<<13568, 256, 0, stream>>>(W0, Wf, ta_in_w, ta_out_w, state, t,
                                       w0_bf, wf_bf, taA_bf, taB_bf, x_bf);

  // h = relu(x @ W0^T + b0)   K padded 270->320
  pgemm<0, 320, 320><<<dim3(64, 8), 512, lds, stream>>>(x_bf, w0_bf, b0, nullptr, h_bf, 1024, 1024);

  // 8 residual blocks
  for (int r = 0; r < 8; r++) {
    pgemm<1, 1024, 1024><<<dim3(64, 8), 512, lds, stream>>>(
        h_bf, rw1_bf + ((size_t)r << 20), rb1 + (r << 10), nullptr, tmp_bf, 1024, 1024);
    pgemm<2, 1024, 1024><<<dim3(64, 8), 512, lds, stream>>>(
        tmp_bf, rw2_bf + ((size_t)r << 20), rb2 + (r << 10), h_bf, h_bf, 1024, 1024);
  }

  // ta path: v2 = x[:, :256] @ taA^T + b ; eh = v2 @ taB^T + b
  gemm_bt<<<dim3(2, 128), 256, 0, stream>>>(x_bf, taA_bf, ta_in_b + 512, v2_bf, 256, 320, 256);
  gemm_bt<<<dim3(2, 128), 256, 0, stream>>>(v2_bf, taB_bf, ta_out_b, eh_bf, 256, 256, 256);

  // out = h @ Wf^T + bf + 0.1*delta (fused, standalone kernel)
  pgemm4<<<dim3(64, 3), 512, lds, stream>>>(h_bf, wf_bf, bfv, eh_bf, state, out,
                                            lp_in_w, lp_in_b, lp_out_w, lp_out_b,
                                            loc_proj_w, loc_proj_b,
                                            loc_back_w, loc_back_b);
}